// Round 1
// baseline (464.770 us; speedup 1.0000x reference)
//
#include <hip/hip_runtime.h>

#define N_NODES 10000
#define N_EDGES 160000

typedef unsigned short u16;
typedef unsigned int   u32;
typedef __bf16 bf16x8 __attribute__((ext_vector_type(8)));
typedef float  f32x4  __attribute__((ext_vector_type(4)));

struct InP { const void* p[22]; };

// ---------------- workspace layout (bytes, all 256-aligned where it matters) ----------------
static constexpr size_t WS_FLAG = 0;                       // int flag (is_bf16)
static constexpr size_t WS_WIN  = 256;                     // f32 [64][16]
static constexpr size_t WS_WQ   = WS_WIN  + 1024*4;        // f32 [16][8]
static constexpr size_t WS_WD   = WS_WQ   + 128*4;         // f32 [8][8]
static constexpr size_t WS_WOUT = WS_WD   + 64*4;          // f32 [16][64]
static constexpr size_t WS_BK1  = WS_WOUT + 1024*4;        // f32 128
static constexpr size_t WS_BK2  = WS_BK1  + 128*4;         // f32 128
static constexpr size_t WS_BK3  = WS_BK2  + 128*4;         // f32 512
static constexpr size_t WS_BV1  = WS_BK3  + 512*4;         // f32 128
static constexpr size_t WS_BV2  = WS_BV1  + 128*4;         // f32 128
static constexpr size_t WS_BV3  = WS_BV2  + 128*4;         // f32 1024
static constexpr size_t WS_BNW  = WS_BV3  + 1024*4;        // f32 64
static constexpr size_t WS_BNB  = WS_BNW  + 64*4;          // f32 64
static constexpr size_t WS_WK1T = WS_BNB  + 64*4;          // bf16 [128][32]  (N-major, K-contig)
static constexpr size_t WS_WK2T = WS_WK1T + 4096*2;        // bf16 [128][128]
static constexpr size_t WS_WK3T = WS_WK2T + 16384*2;       // bf16 [512][128]
static constexpr size_t WS_WV1T = WS_WK3T + 65536*2;       // bf16 [128][32]
static constexpr size_t WS_WV2T = WS_WV1T + 4096*2;        // bf16 [128][128]
static constexpr size_t WS_WV3T = WS_WV2T + 16384*2;       // bf16 [1024][128]
static constexpr size_t WS_NODE = WS_WV3T + 131072*2;      // f32 [N][64]
static constexpr size_t WS_T    = WS_NODE + (size_t)N_NODES*64*4;   // f32 [N][16]
static constexpr size_t WS_Q    = WS_T    + (size_t)N_NODES*16*4;   // f32 [N][8]
static constexpr size_t WS_A    = WS_Q    + (size_t)N_NODES*8*4;    // f32 [E]
static constexpr size_t WS_V    = WS_A    + (size_t)N_EDGES*4;      // f32 [E][16]
static constexpr size_t WS_MU   = WS_V    + (size_t)N_EDGES*16*4;   // u32 [N]  (mapped max)
static constexpr size_t WS_Z    = WS_MU   + (size_t)N_NODES*4;      // f32 [N]
static constexpr size_t WS_AGG  = WS_Z    + (size_t)N_NODES*4;      // f32 [N][16]
static constexpr size_t WS_BNS  = WS_AGG  + (size_t)N_NODES*16*4;   // f32 [64]
static constexpr size_t WS_BNQ  = WS_BNS  + 64*4;                   // f32 [64]
static constexpr size_t WS_OUTP = WS_BNQ  + 64*4;                   // f32 [N][64]
static constexpr size_t ZERO_OFF = WS_MU;
static constexpr size_t ZERO_LEN = WS_OUTP - WS_MU;

// ---------------- helpers ----------------
__device__ __forceinline__ float loadf(const void* p, long i, int isbf){
  if(isbf){
    u32 x = ((u32)((const u16*)p)[i]) << 16;
    return __uint_as_float(x);
  }
  return ((const float*)p)[i];
}
__device__ __forceinline__ u16 f2b(float f){  // RNE f32 -> bf16
  u32 u = __float_as_uint(f);
  u += 0x7fffu + ((u >> 16) & 1u);
  return (u16)(u >> 16);
}
__device__ __forceinline__ bf16x8 ld8(const u16* p){
  uint4 v = *(const uint4*)p;
  return __builtin_bit_cast(bf16x8, v);
}

// ---------------- kernels ----------------
__global__ void k_detect(const void* edge_data, int* flag){
  // even ushort offsets: sane bf16 exponents iff storage is bf16
  int lane = threadIdx.x;
  u16 v = ((const u16*)edge_data)[lane*2];
  int ex = (v >> 7) & 0xFF;
  int sane = (ex >= 100 && ex <= 140) ? 1 : 0;
  unsigned long long b = __ballot(sane);
  if(lane == 0) flag[0] = (__popcll(b) >= 48) ? 1 : 0;
}

__global__ void k_convert(InP in, char* ws){
  const int isbf = *(const int*)(ws + WS_FLAG);
  long idx = (long)blockIdx.x*256 + threadIdx.x;
  // f32 copy segments
  const int    fsrc[13] = {0,4,5,6,7,9,11,13,15,17,19,20,21};
  const int    fcnt[13] = {640000,1024,128,64,1024,128,128,512,128,128,1024,64,64};
  const size_t fdst[13] = {WS_NODE,WS_WIN,WS_WQ,WS_WD,WS_WOUT,WS_BK1,WS_BK2,WS_BK3,WS_BV1,WS_BV2,WS_BV3,WS_BNW,WS_BNB};
  const long F_TOTAL = 644416;
  if(idx < F_TOTAL){
    long g = idx;
    for(int s=0;s<13;s++){
      if(g < fcnt[s]){ ((float*)(ws+fdst[s]))[g] = loadf(in.p[fsrc[s]], g, isbf); return; }
      g -= fcnt[s];
    }
    return;
  }
  long g = idx - F_TOTAL;
  // bf16 transpose segments: src [K][N] -> dst [N][K]
  const int    tsrc[6] = {8,10,12,14,16,18};
  const int    tK[6]   = {32,128,128,32,128,128};
  const int    tN[6]   = {128,128,512,128,128,1024};
  const size_t tdst[6] = {WS_WK1T,WS_WK2T,WS_WK3T,WS_WV1T,WS_WV2T,WS_WV3T};
  for(int s=0;s<6;s++){
    long cnt = (long)tK[s]*tN[s];
    if(g < cnt){
      int n = (int)(g / tK[s]), k = (int)(g % tK[s]);
      ((u16*)(ws+tdst[s]))[(long)n*tK[s] + k] = f2b(loadf(in.p[tsrc[s]], (long)k*tN[s] + n, isbf));
      return;
    }
    g -= cnt;
  }
}

__global__ void k_t(char* ws){
  __shared__ float sW[1024];
  const float* nodef = (const float*)(ws+WS_NODE);
  const float* W = (const float*)(ws+WS_WIN);
  float* t = (float*)(ws+WS_T);
  for(int i=threadIdx.x;i<1024;i+=256) sW[i]=W[i];
  __syncthreads();
  int idx = blockIdx.x*256+threadIdx.x;
  if(idx >= N_NODES*16) return;
  int n = idx>>4, j = idx&15;
  float acc=0.f;
  #pragma unroll 8
  for(int i=0;i<64;i++) acc += nodef[n*64+i]*sW[i*16+j];
  t[idx] = acc*0.125f;   // 1/sqrt(64)
}

__global__ void k_q(char* ws){
  __shared__ float sW[128];
  const float* t = (const float*)(ws+WS_T);
  const float* W = (const float*)(ws+WS_WQ);
  float* q = (float*)(ws+WS_Q);
  for(int i=threadIdx.x;i<128;i+=256) sW[i]=W[i];
  __syncthreads();
  int idx = blockIdx.x*256+threadIdx.x;
  if(idx >= N_NODES*8) return;
  int n = idx>>3, j = idx&7;
  float acc=0.f;
  #pragma unroll
  for(int i=0;i<16;i++) acc += t[n*16+i]*sW[i*8+j];
  q[idx] = acc*0.25f;    // 1/sqrt(16)
}

// Fused per-edge kernel: MLPs via MFMA, contraction to k/v, attention logit.
__global__ __launch_bounds__(256,2) void k_edges(InP in, char* ws){
  const int isbf = *(const int*)(ws + WS_FLAG);
  const int* ei = (const int*)in.p[1];
  const float* t_ws = (const float*)(ws + WS_T);
  const float* q_ws = (const float*)(ws + WS_Q);
  float* a_ws = (float*)(ws + WS_A);
  float* v_ws = (float*)(ws + WS_V);
  const float* wdf = (const float*)(ws + WS_WD);

  __shared__ __align__(16) u16 sED[64*40];    // edge feats bf16, stride 40
  __shared__ __align__(16) u16 sH1[64*136];   // h1 bf16, stride 136
  __shared__ __align__(16) u16 sH2[64*136];   // h2 bf16
  __shared__ __align__(16) u16 sWT[32*136];   // weight chunk [32 n][K<=128]
  __shared__ float sTS[64*16];
  __shared__ float sSH[64*4];
  __shared__ float sQD[64*8];
  __shared__ float sK[64*8];
  __shared__ float sV[64*16];
  __shared__ float sWD[64];

  const int tid = threadIdx.x;
  const int e0 = blockIdx.x * 64;
  const int wave = tid >> 6, lane = tid & 63;
  const int lrow = lane & 15, lquad = lane >> 4;
  const int we0 = wave * 16;

  // ---- staging ----
  for(int idx = tid; idx < 2048; idx += 256){
    int e = idx >> 5, c = idx & 31;
    sED[e*40 + c] = f2b(loadf(in.p[2], (long)(e0+e)*32 + c, isbf));
  }
  for(int idx = tid; idx < 1024; idx += 256){
    int e = idx >> 4, a = idx & 15;
    int src = ei[e0 + e];
    sTS[idx] = t_ws[src*16 + a];
  }
  for(int idx = tid; idx < 512; idx += 256){
    int e = idx >> 3, b = idx & 7;
    int dst = ei[N_EDGES + e0 + e];
    sQD[idx] = q_ws[dst*8 + b];
  }
  {
    int idx = tid;
    if(idx < 256){
      int e = idx >> 2, s = idx & 3;
      sSH[idx] = loadf(in.p[3], (long)(e0+e)*4 + s, isbf);
    }
  }
  if(tid < 64) sWD[tid] = wdf[tid];
  for(int idx = tid; idx < 512; idx += 256) sK[idx] = 0.f;
  for(int idx = tid; idx < 1024; idx += 256) sV[idx] = 0.f;
  __syncthreads();

  // dense: O[e][n] = relu(A[e][:K] @ WT[n][:K] + bias[n]), wave w owns edge rows [16w,16w+16)
  auto dense = [&](const u16* A, int As, int K, const u16* WTg, const float* bias, int N, u16* O){
    const int nk = K >> 5;
    for(int nc = 0; nc < N; nc += 32){
      __syncthreads();
      for(int idx = tid; idx < 32*(K>>3); idx += 256){
        int r = idx/(K>>3), part = idx%(K>>3);
        *(uint4*)&sWT[r*136 + part*8] = *(const uint4*)&WTg[(long)(nc+r)*K + part*8];
      }
      __syncthreads();
      bf16x8 af[4];
      for(int kk = 0; kk < nk; kk++)
        af[kk] = ld8(&A[(we0+lrow)*As + kk*32 + lquad*8]);
      for(int nt = 0; nt < 2; nt++){
        f32x4 c = {0.f,0.f,0.f,0.f};
        for(int kk = 0; kk < nk; kk++){
          bf16x8 bf = ld8(&sWT[(nt*16+lrow)*136 + kk*32 + lquad*8]);
          c = __builtin_amdgcn_mfma_f32_16x16x32_bf16(af[kk], bf, c, 0, 0, 0);
        }
        int n = nc + nt*16 + lrow;        // C/D: col = lane&15
        float bb = bias[n];
        #pragma unroll
        for(int r = 0; r < 4; r++){
          int e = we0 + lquad*4 + r;      // C/D: row = quad*4 + reg
          float h = c[r] + bb;
          h = h > 0.f ? h : 0.f;
          O[e*136 + n] = f2b(h);
        }
      }
    }
  };

  // matvec+contract: wk[e][j] = h2[e][:]@WT[j][:]+bias[j]; k/v[e][b] += ts[e][a]*sh[e][s]*wk
  auto matvec = [&](const u16* WTg, const float* bias, int N, int isval){
    float kp[4] = {0.f,0.f,0.f,0.f};
    for(int nc = 0; nc < N; nc += 32){
      __syncthreads();
      for(int idx = tid; idx < 512; idx += 256){
        int r = idx >> 4, part = idx & 15;
        *(uint4*)&sWT[r*136 + part*8] = *(const uint4*)&WTg[(long)(nc+r)*128 + part*8];
      }
      __syncthreads();
      bf16x8 af[4];
      #pragma unroll
      for(int kk = 0; kk < 4; kk++)
        af[kk] = ld8(&sH2[(we0+lrow)*136 + kk*32 + lquad*8]);
      for(int nt = 0; nt < 2; nt++){
        f32x4 c = {0.f,0.f,0.f,0.f};
        #pragma unroll
        for(int kk = 0; kk < 4; kk++){
          bf16x8 bf = ld8(&sWT[(nt*16+lrow)*136 + kk*32 + lquad*8]);
          c = __builtin_amdgcn_mfma_f32_16x16x32_bf16(af[kk], bf, c, 0, 0, 0);
        }
        int j = nc + nt*16 + lrow;
        int a = isval ? (j>>6) : (j>>5);          // wv:[16][4][16]  wk:[16][4][8]
        int s = isval ? ((j>>4)&3) : ((j>>3)&3);
        float bb = bias[j];
        #pragma unroll
        for(int r = 0; r < 4; r++){
          int e = we0 + lquad*4 + r;
          float w = c[r] + bb;
          kp[r] += sTS[e*16+a] * sSH[e*4+s] * w;
        }
      }
    }
    if(isval){
      #pragma unroll
      for(int r = 0; r < 4; r++){
        int e = we0 + lquad*4 + r;
        sV[e*16 + lrow] = kp[r]*0.125f;           // unique (e, bo=lane&15) per (lane,reg)
      }
    } else {
      int b = lane & 7;                            // 2 lanes (l, l^8) share (e,b)
      #pragma unroll
      for(int r = 0; r < 4; r++){
        int e = we0 + lquad*4 + r;
        atomicAdd(&sK[e*8 + b], kp[r]*0.125f);
      }
    }
  };

  dense(sED, 40, 32,  (const u16*)(ws+WS_WK1T), (const float*)(ws+WS_BK1), 128, sH1);
  dense(sH1, 136, 128,(const u16*)(ws+WS_WK2T), (const float*)(ws+WS_BK2), 128, sH2);
  matvec((const u16*)(ws+WS_WK3T), (const float*)(ws+WS_BK3), 512, 0);
  dense(sED, 40, 32,  (const u16*)(ws+WS_WV1T), (const float*)(ws+WS_BV1), 128, sH1);
  dense(sH1, 136, 128,(const u16*)(ws+WS_WV2T), (const float*)(ws+WS_BV2), 128, sH2);
  matvec((const u16*)(ws+WS_WV3T), (const float*)(ws+WS_BV3), 1024, 1);
  __syncthreads();

  for(int idx = tid; idx < 1024; idx += 256)
    v_ws[(long)e0*16 + idx] = sV[idx];
  if(tid < 64){
    int e = tid;
    float acc = 0.f;
    #pragma unroll
    for(int a = 0; a < 8; a++){
      float qa = sQD[e*8 + a];
      #pragma unroll
      for(int b = 0; b < 8; b++)
        acc += qa * sWD[a*8 + b] * sK[e*8 + b];
    }
    a_ws[e0 + e] = acc * 0.125f;   // 1/sqrt(64)
  }
}

__global__ void k_amax(const int* ei, char* ws){
  int i = blockIdx.x*256+threadIdx.x;
  if(i >= N_EDGES) return;
  float a = ((const float*)(ws+WS_A))[i];
  u32 u = __float_as_uint(a);
  u = (u & 0x80000000u) ? ~u : (u | 0x80000000u);  // order-preserving map
  atomicMax((u32*)(ws+WS_MU) + ei[N_EDGES + i], u);
}

__global__ void k_pz(const int* ei, char* ws){
  long i = (long)blockIdx.x*256 + threadIdx.x;
  if(i >= (long)N_EDGES*16) return;
  int e = (int)(i >> 4), c = (int)(i & 15);
  int dst = ei[N_EDGES + e];
  u32 mu = ((const u32*)(ws+WS_MU))[dst];
  float m = (mu & 0x80000000u) ? __uint_as_float(mu ^ 0x80000000u) : __uint_as_float(~mu);
  float p = __expf(((const float*)(ws+WS_A))[e] - m);
  if(c == 0) atomicAdd((float*)(ws+WS_Z) + dst, p);
  float v = ((const float*)(ws+WS_V))[i];
  atomicAdd((float*)(ws+WS_AGG) + dst*16 + c, p*v);
}

__global__ void k7a(char* ws){
  __shared__ float sW[1024];
  const float* W = (const float*)(ws+WS_WOUT);
  for(int i=threadIdx.x;i<1024;i+=256) sW[i]=W[i];
  __syncthreads();
  int idx = blockIdx.x*256+threadIdx.x;
  if(idx >= N_NODES*64) return;
  int n = idx>>6, c = idx&63;
  float z = ((const float*)(ws+WS_Z))[n];
  float inv = z > 0.f ? 0.25f/z : 0.f;   // /sqrt(16) folded in
  const float* agg = (const float*)(ws+WS_AGG) + n*16;
  float acc=0.f;
  #pragma unroll
  for(int j=0;j<16;j++) acc += agg[j]*sW[j*64+c];
  ((float*)(ws+WS_OUTP))[idx] = acc*inv + ((const float*)(ws+WS_NODE))[idx];
}

__global__ void k7b(char* ws){
  __shared__ float ls[256], lq[256];
  const float* op = (const float*)(ws+WS_OUTP);
  int t = threadIdx.x, c = t&63, rg = t>>6;
  float s=0.f, q=0.f;
  for(int jj=rg; jj<40; jj+=4){
    int n = blockIdx.x + 256*jj;
    if(n < N_NODES){ float x = op[n*64+c]; s += x; q += x*x; }
  }
  ls[t]=s; lq[t]=q;
  __syncthreads();
  if(rg==0){
    s = ls[c]+ls[c+64]+ls[c+128]+ls[c+192];
    q = lq[c]+lq[c+64]+lq[c+128]+lq[c+192];
    atomicAdd((float*)(ws+WS_BNS)+c, s);
    atomicAdd((float*)(ws+WS_BNQ)+c, q);
  }
}

__global__ void k7c(char* ws, void* d_out){
  const int isbf = *(const int*)(ws+WS_FLAG);
  int idx = blockIdx.x*256+threadIdx.x;
  if(idx >= N_NODES*64) return;
  int c = idx&63;
  float s  = ((const float*)(ws+WS_BNS))[c];
  float qq = ((const float*)(ws+WS_BNQ))[c];
  float mean = s * (1.f/N_NODES);
  float var  = qq * (1.f/N_NODES) - mean*mean;
  float sc = rsqrtf(var + 1e-5f) * ((const float*)(ws+WS_BNW))[c];
  float val = (((const float*)(ws+WS_OUTP))[idx] - mean)*sc + ((const float*)(ws+WS_BNB))[c];
  if(isbf) ((u16*)d_out)[idx] = f2b(val);
  else     ((float*)d_out)[idx] = val;
}

extern "C" void kernel_launch(void* const* d_in, const int* in_sizes, int n_in,
                              void* d_out, int out_size, void* d_ws, size_t ws_size,
                              hipStream_t stream){
  InP in;
  for(int i=0;i<22;i++) in.p[i] = d_in[i];
  char* ws = (char*)d_ws;

  hipMemsetAsync(ws + ZERO_OFF, 0, ZERO_LEN, stream);
  k_detect<<<1,64,0,stream>>>((const void*)d_in[2], (int*)(ws+WS_FLAG));
  k_convert<<<3446,256,0,stream>>>(in, ws);
  k_t<<<625,256,0,stream>>>(ws);
  k_q<<<313,256,0,stream>>>(ws);
  k_edges<<<2500,256,0,stream>>>(in, ws);
  k_amax<<<625,256,0,stream>>>((const int*)d_in[1], ws);
  k_pz<<<10000,256,0,stream>>>((const int*)d_in[1], ws);
  k7a<<<2500,256,0,stream>>>(ws);
  k7b<<<256,256,0,stream>>>(ws);
  k7c<<<2500,256,0,stream>>>(ws, d_out);
}

// Round 2
// 402.798 us; speedup vs baseline: 1.1539x; 1.1539x over previous
//
#include <hip/hip_runtime.h>

#define N_NODES 10000
#define N_EDGES 160000

typedef unsigned short u16;
typedef unsigned int   u32;
typedef __bf16 bf16x8 __attribute__((ext_vector_type(8)));
typedef float  f32x4  __attribute__((ext_vector_type(4)));
typedef unsigned short u16x4 __attribute__((ext_vector_type(4)));

struct InP { const void* p[22]; };

// ---------------- workspace layout ----------------
static constexpr size_t WS_FLAG = 0;
static constexpr size_t WS_WIN  = 256;                    // f32 [64][16]
static constexpr size_t WS_WQ   = WS_WIN  + 4096;         // f32 [16][8]
static constexpr size_t WS_WD   = WS_WQ   + 512;          // f32 [8][8]
static constexpr size_t WS_WOUT = WS_WD   + 256;          // f32 [16][64]
static constexpr size_t WS_BK1  = WS_WOUT + 4096;         // f32 128
static constexpr size_t WS_BK2  = WS_BK1  + 512;
static constexpr size_t WS_BK3  = WS_BK2  + 512;          // f32 512
static constexpr size_t WS_BV1  = WS_BK3  + 2048;
static constexpr size_t WS_BV2  = WS_BV1  + 512;
static constexpr size_t WS_BV3  = WS_BV2  + 512;          // f32 1024
static constexpr size_t WS_BNW  = WS_BV3  + 4096;         // f32 64
static constexpr size_t WS_BNB  = WS_BNW  + 256;
static constexpr size_t WS_WK1T = WS_BNB  + 256;          // bf16 [128][32]  (N-major, K-contig)
static constexpr size_t WS_WK2T = WS_WK1T + 8192;         // bf16 [128][128]
static constexpr size_t WS_WK3T = WS_WK2T + 32768;        // bf16 [512][128]
static constexpr size_t WS_WV1T = WS_WK3T + 131072;       // bf16 [128][32]
static constexpr size_t WS_WV2T = WS_WV1T + 8192;         // bf16 [128][128]
static constexpr size_t WS_WV3T = WS_WV2T + 32768;        // bf16 [1024][128]
static constexpr size_t WS_T    = WS_WV3T + 262144;       // f32 [N][16]
static constexpr size_t WS_Q    = WS_T    + (size_t)N_NODES*16*4;  // f32 [N][8]
static constexpr size_t WS_Z    = WS_Q    + (size_t)N_NODES*8*4;   // f32 [N]
static constexpr size_t WS_AGG  = WS_Z    + (size_t)N_NODES*4;     // f32 [N][16]
static constexpr size_t WS_BNS  = WS_AGG  + (size_t)N_NODES*16*4;  // f32 64
static constexpr size_t WS_BNQ  = WS_BNS  + 256;
static constexpr size_t WS_OUTP = WS_BNQ  + 256;          // f32 [N][64]
static constexpr size_t ZERO_OFF = WS_Z;
static constexpr size_t ZERO_LEN = WS_OUTP - WS_Z;        // Z + AGG + BNS + BNQ

// ---------------- helpers ----------------
__device__ __forceinline__ float loadf(const void* p, long i, int isbf){
  if(isbf){
    u32 x = ((u32)((const u16*)p)[i]) << 16;
    return __uint_as_float(x);
  }
  return ((const float*)p)[i];
}
__device__ __forceinline__ u16 f2b(float f){  // RNE f32 -> bf16
  u32 u = __float_as_uint(f);
  u += 0x7fffu + ((u >> 16) & 1u);
  return (u16)(u >> 16);
}
__device__ __forceinline__ float b2f(u16 v){
  return __uint_as_float(((u32)v) << 16);
}
__device__ __forceinline__ bf16x8 ld8(const u16* p){
  uint4 v = *(const uint4*)p;
  return __builtin_bit_cast(bf16x8, v);
}

// ---------------- kernels ----------------
__global__ void k_detect(const void* edge_data, int* flag){
  int lane = threadIdx.x;
  u16 v = ((const u16*)edge_data)[lane*2];
  int ex = (v >> 7) & 0xFF;
  int sane = (ex >= 100 && ex <= 140) ? 1 : 0;
  unsigned long long b = __ballot(sane);
  if(lane == 0) flag[0] = (__popcll(b) >= 48) ? 1 : 0;
}

__global__ void k_convert(InP in, char* ws){
  const int isbf = *(const int*)(ws + WS_FLAG);
  long idx = (long)blockIdx.x*256 + threadIdx.x;
  const int    fsrc[12] = {4,5,6,7,9,11,13,15,17,19,20,21};
  const int    fcnt[12] = {1024,128,64,1024,128,128,512,128,128,1024,64,64};
  const size_t fdst[12] = {WS_WIN,WS_WQ,WS_WD,WS_WOUT,WS_BK1,WS_BK2,WS_BK3,WS_BV1,WS_BV2,WS_BV3,WS_BNW,WS_BNB};
  const long F_TOTAL = 4416;
  if(idx < F_TOTAL){
    long g = idx;
    for(int s=0;s<12;s++){
      if(g < fcnt[s]){ ((float*)(ws+fdst[s]))[g] = loadf(in.p[fsrc[s]], g, isbf); return; }
      g -= fcnt[s];
    }
    return;
  }
  long g = idx - F_TOTAL;
  const int    tsrc[6] = {8,10,12,14,16,18};
  const int    tK[6]   = {32,128,128,32,128,128};
  const int    tN[6]   = {128,128,512,128,128,1024};
  const size_t tdst[6] = {WS_WK1T,WS_WK2T,WS_WK3T,WS_WV1T,WS_WV2T,WS_WV3T};
  for(int s=0;s<6;s++){
    long cnt = (long)tK[s]*tN[s];
    if(g < cnt){
      int n = (int)(g / tK[s]), k = (int)(g % tK[s]);
      ((u16*)(ws+tdst[s]))[(long)n*tK[s] + k] = f2b(loadf(in.p[tsrc[s]], (long)k*tN[s] + n, isbf));
      return;
    }
    g -= cnt;
  }
}

// fused t and q (per-node linears)
__global__ void k_tq(InP in, char* ws){
  const int isbf = *(const int*)(ws + WS_FLAG);
  __shared__ float sWin[1024];
  __shared__ float sWq[128];
  __shared__ float sN[1024];
  __shared__ float sT[256];
  float* t_ws = (float*)(ws+WS_T);
  float* q_ws = (float*)(ws+WS_Q);
  int tid = threadIdx.x;
  for(int i=tid;i<1024;i+=256) sWin[i] = ((const float*)(ws+WS_WIN))[i];
  if(tid<128) sWq[tid] = ((const float*)(ws+WS_WQ))[tid];
  int n0 = blockIdx.x*16;
  for(int i=tid;i<1024;i+=256) sN[i] = loadf(in.p[0], (long)n0*64 + i, isbf);
  __syncthreads();
  int ni = tid>>4, j = tid&15;
  float acc = 0.f;
  #pragma unroll 8
  for(int i=0;i<64;i++) acc += sN[ni*64+i]*sWin[i*16+j];
  float t = acc*0.125f;                 // 1/sqrt(64)
  t_ws[(n0+ni)*16+j] = t;
  sT[tid] = t;
  __syncthreads();
  if(tid<128){
    int n2 = tid>>3, b = tid&7;
    float a2 = 0.f;
    #pragma unroll
    for(int jj=0;jj<16;jj++) a2 += sT[n2*16+jj]*sWq[jj*8+b];
    q_ws[(n0+n2)*8+b] = a2*0.25f;       // 1/sqrt(16)
  }
}

// Fused per-edge kernel: MLPs via MFMA (wave-owns-cols, weights from L2),
// contraction, logit, exp, z/agg atomics — all in one pass.
__global__ __launch_bounds__(256,3) void k_edges(InP in, char* ws){
  const int isbf = *(const int*)(ws + WS_FLAG);
  const int* ei = (const int*)in.p[1];
  const float* t_ws = (const float*)(ws + WS_T);
  const float* q_ws = (const float*)(ws + WS_Q);
  float* Zp  = (float*)(ws + WS_Z);
  float* AGG = (float*)(ws + WS_AGG);

  __shared__ __align__(16) char smem[54272];
  u16*   sED = (u16*)smem;               // [64][40] bf16 (5120 B); reused at tail: sP/sDst
  u16*   sH1 = (u16*)(smem + 5120);      // [64][136] bf16
  u16*   sH2 = (u16*)(smem + 22528);     // [64][136] bf16
  u16*   sPT = (u16*)(smem + 39936);     // bf16 [as=64][e=64]  (ts*sh)
  float* sK  = (float*)(smem + 48128);   // [64][8];  staging alias: sh f32[64][4]
  float* sV  = (float*)(smem + 50176);   // [64][16]; staging alias: ts f32[64][16]
  float* sP  = (float*)smem;             // [64] p (after sED dead)
  int*   sDst= (int*)(smem + 256);       // [64] dst

  const int tid  = threadIdx.x;
  const int e0   = blockIdx.x * 64;
  const int lane = tid & 63, wv = tid >> 6;
  const int lrow = lane & 15, lquad = lane >> 4;

  // ---- staging ----
  for(int idx = tid; idx < 2048; idx += 256){
    int e = idx >> 5, c = idx & 31;
    sED[e*40 + c] = f2b(loadf(in.p[2], (long)(e0+e)*32 + c, isbf));
  }
  for(int idx = tid; idx < 1024; idx += 256){
    int e = idx >> 4, a = idx & 15;
    sV[idx] = t_ws[ei[e0+e]*16 + a];          // ts staged into sV space
  }
  {
    int e = tid >> 2, s = tid & 3;
    sK[tid] = loadf(in.p[3], (long)(e0+e)*4 + s, isbf);   // sh into sK space
  }
  __syncthreads();
  for(int idx = tid; idx < 4096; idx += 256){
    int e = idx & 63, as = idx >> 6;
    sPT[as*64 + e] = f2b(sV[e*16 + (as>>2)] * sK[e*4 + (as&3)]);
  }
  __syncthreads();
  for(int idx = tid; idx < 1536; idx += 256) sK[idx] = 0.f;   // zeros sK(512)+sV(1024), contiguous

  // dense: O[e][n] = relu(A[e][:K] @ WT[n][:K] + bias[n]); wave owns cols [32w,32w+32)
  // mfma(W_frag, A_frag): D.row(quad*4+r) <-> W-row n, D.col(lrow) <-> edge e
  auto dense = [&](const u16* A, int As, int K, const u16* WTg, const float* biasg, u16* O){
    const int nk = K >> 5;
    const int nb = wv*32;
    bf16x8 bf[2][4]; f32x4 bb[2];
    for(int nt=0;nt<2;nt++){
      for(int kk=0;kk<nk;kk++)
        bf[nt][kk] = ld8(&WTg[(long)(nb+nt*16+lrow)*K + kk*32 + lquad*8]);
      bb[nt] = *(const f32x4*)&biasg[nb + nt*16 + lquad*4];
    }
    for(int et=0;et<4;et++){
      bf16x8 af[4];
      for(int kk=0;kk<nk;kk++)
        af[kk] = ld8(&A[(et*16+lrow)*As + kk*32 + lquad*8]);
      const int e = et*16 + lrow;
      for(int nt=0;nt<2;nt++){
        f32x4 c = {0.f,0.f,0.f,0.f};
        for(int kk=0;kk<nk;kk++)
          c = __builtin_amdgcn_mfma_f32_16x16x32_bf16(bf[nt][kk], af[kk], c, 0, 0, 0);
        u16x4 pk;
        #pragma unroll
        for(int r=0;r<4;r++){
          float h = c[r] + bb[nt][r];
          h = h > 0.f ? h : 0.f;
          pk[r] = f2b(h);
        }
        *(u16x4*)&O[e*136 + nb + nt*16 + lquad*4] = pk;   // 4 consecutive cols, b64 store
      }
    }
  };

  // matvec+contract: wave owns N/4 cols; lane's 4 rows share one P_T index
  auto matvec = [&](const u16* WTg, const float* biasg, int N, int isval){
    const int cb = wv*(N>>2);
    float kp[16];
    #pragma unroll
    for(int i=0;i<16;i++) kp[i]=0.f;
    for(int nc=0; nc<(N>>2); nc+=32){
      bf16x8 bf[2][4]; f32x4 bb[2];
      for(int nt=0;nt<2;nt++){
        #pragma unroll
        for(int kk=0;kk<4;kk++)
          bf[nt][kk] = ld8(&WTg[(long)(cb+nc+nt*16+lrow)*128 + kk*32 + lquad*8]);
        bb[nt] = *(const f32x4*)&biasg[cb + nc + nt*16 + lquad*4];
      }
      for(int et=0;et<4;et++){
        bf16x8 af[4];
        #pragma unroll
        for(int kk=0;kk<4;kk++)
          af[kk] = ld8(&sH2[(et*16+lrow)*136 + kk*32 + lquad*8]);
        const int e = et*16 + lrow;
        for(int nt=0;nt<2;nt++){
          f32x4 c = {0.f,0.f,0.f,0.f};
          #pragma unroll
          for(int kk=0;kk<4;kk++)
            c = __builtin_amdgcn_mfma_f32_16x16x32_bf16(bf[nt][kk], af[kk], c, 0, 0, 0);
          int j0 = cb + nc + nt*16 + lquad*4;      // rows j0..j0+3 (r-loop)
          int as = j0 >> (isval ? 4 : 3);          // same for all r (j0 % 4 == 0)
          float pv = b2f(sPT[as*64 + e]);
          #pragma unroll
          for(int r=0;r<4;r++)
            kp[et*4+r] += pv * (c[r] + bb[nt][r]);
        }
      }
    }
    if(isval){
      for(int et=0;et<4;et++){
        int e = et*16 + lrow;                      // b = lquad*4+r, unique per wave
        #pragma unroll
        for(int r=0;r<4;r++)
          atomicAdd(&sV[e*16 + lquad*4 + r], kp[et*4+r]*0.125f);
      }
    } else {
      int b0 = (lquad & 1)*4;                      // b = (lquad*4+r)&7
      for(int et=0;et<4;et++){
        int e = et*16 + lrow;
        #pragma unroll
        for(int r=0;r<4;r++)
          atomicAdd(&sK[e*8 + b0 + r], kp[et*4+r]*0.125f);
      }
    }
  };

  dense(sED, 40, 32,  (const u16*)(ws+WS_WK1T), (const float*)(ws+WS_BK1), sH1); __syncthreads();
  dense(sH1, 136, 128,(const u16*)(ws+WS_WK2T), (const float*)(ws+WS_BK2), sH2); __syncthreads();
  matvec((const u16*)(ws+WS_WK3T), (const float*)(ws+WS_BK3), 512, 0);           __syncthreads();
  dense(sED, 40, 32,  (const u16*)(ws+WS_WV1T), (const float*)(ws+WS_BV1), sH1); __syncthreads();
  dense(sH1, 136, 128,(const u16*)(ws+WS_WV2T), (const float*)(ws+WS_BV2), sH2); __syncthreads();
  matvec((const u16*)(ws+WS_WV3T), (const float*)(ws+WS_BV3), 1024, 1);          __syncthreads();

  // ---- logit + exp + z (wave 0), then p*v -> AGG (all threads) ----
  if(tid < 64){
    int e = tid;
    int dst = ei[N_EDGES + e0 + e];
    const float* wdf = (const float*)(ws + WS_WD);
    float acc = 0.f;
    #pragma unroll
    for(int a=0;a<8;a++){
      float qa = q_ws[dst*8 + a];
      #pragma unroll
      for(int b=0;b<8;b++)
        acc += qa * wdf[a*8+b] * sK[e*8+b];
    }
    float p = __expf(acc * 0.125f);     // softmax shift-invariant; |logit| <~ 4, exp safe
    atomicAdd(Zp + dst, p);
    sP[e] = p;                          // sED region is dead now
    sDst[e] = dst;
  }
  __syncthreads();
  for(int idx = tid; idx < 1024; idx += 256){
    int e = idx >> 4;
    atomicAdd(AGG + (long)sDst[e]*16 + (idx & 15), sP[e]*sV[idx]);
  }
}

// out-linear + residual + BN partial sums (fused)
__global__ void k7a(InP in, char* ws){
  const int isbf = *(const int*)(ws + WS_FLAG);
  __shared__ float sWo[1024];
  __shared__ float ls[256], lq[256];
  int tid = threadIdx.x;
  for(int i=tid;i<1024;i+=256) sWo[i] = ((const float*)(ws+WS_WOUT))[i];
  __syncthreads();
  const float* AGG = (const float*)(ws+WS_AGG);
  const float* Zp  = (const float*)(ws+WS_Z);
  float* OUTP = (float*)(ws+WS_OUTP);
  int c = tid & 63, r4 = tid >> 6;
  float s=0.f, q=0.f;
  for(int it=0; it<20; it++){
    int n = blockIdx.x*80 + it*4 + r4;      // 125 blocks * 80 = 10000 exactly
    float z = Zp[n];
    float inv = z > 0.f ? 0.25f/z : 0.f;    // 1/sqrt(16) folded
    const float* ag = AGG + (long)n*16;
    float acc = 0.f;
    #pragma unroll
    for(int j=0;j<16;j++) acc += ag[j]*sWo[j*64+c];
    float o = acc*inv + loadf(in.p[0], (long)n*64 + c, isbf);
    OUTP[(long)n*64+c] = o;
    s += o; q += o*o;
  }
  ls[tid]=s; lq[tid]=q;
  __syncthreads();
  if(tid < 64){
    float ss = ls[tid]+ls[tid+64]+ls[tid+128]+ls[tid+192];
    float qq = lq[tid]+lq[tid+64]+lq[tid+128]+lq[tid+192];
    atomicAdd((float*)(ws+WS_BNS)+tid, ss);
    atomicAdd((float*)(ws+WS_BNQ)+tid, qq);
  }
}

__global__ void k7c(char* ws, void* d_out){
  const int isbf = *(const int*)(ws + WS_FLAG);
  int idx = blockIdx.x*256 + threadIdx.x;
  if(idx >= N_NODES*64) return;
  int c = idx & 63;
  float s  = ((const float*)(ws+WS_BNS))[c];
  float qq = ((const float*)(ws+WS_BNQ))[c];
  float mean = s * (1.f/N_NODES);
  float var  = qq * (1.f/N_NODES) - mean*mean;
  float sc = rsqrtf(var + 1e-5f) * ((const float*)(ws+WS_BNW))[c];
  float val = (((const float*)(ws+WS_OUTP))[idx] - mean)*sc + ((const float*)(ws+WS_BNB))[c];
  if(isbf) ((u16*)d_out)[idx] = f2b(val);
  else     ((float*)d_out)[idx] = val;
}

extern "C" void kernel_launch(void* const* d_in, const int* in_sizes, int n_in,
                              void* d_out, int out_size, void* d_ws, size_t ws_size,
                              hipStream_t stream){
  InP in;
  for(int i=0;i<22;i++) in.p[i] = d_in[i];
  char* ws = (char*)d_ws;

  hipMemsetAsync(ws + ZERO_OFF, 0, ZERO_LEN, stream);
  k_detect<<<1,64,0,stream>>>((const void*)d_in[2], (int*)(ws+WS_FLAG));
  k_convert<<<1378,256,0,stream>>>(in, ws);
  k_tq<<<625,256,0,stream>>>(in, ws);
  k_edges<<<2500,256,0,stream>>>(in, ws);
  k7a<<<125,256,0,stream>>>(in, ws);
  k7c<<<2500,256,0,stream>>>(ws, d_out);
}

// Round 3
// 321.917 us; speedup vs baseline: 1.4438x; 1.2513x over previous
//
#include <hip/hip_runtime.h>

#define N_NODES 10000
#define N_EDGES 160000

typedef unsigned short u16;
typedef unsigned int   u32;
typedef __bf16 bf16x8 __attribute__((ext_vector_type(8)));
typedef float  f32x4  __attribute__((ext_vector_type(4)));
typedef unsigned short u16x4 __attribute__((ext_vector_type(4)));

struct InP { const void* p[22]; };

// ---------------- workspace layout ----------------
static constexpr size_t WS_FLAG = 0;
static constexpr size_t WS_WIN  = 256;                    // f32 [64][16]
static constexpr size_t WS_WQ   = WS_WIN  + 4096;         // f32 [16][8]
static constexpr size_t WS_WD   = WS_WQ   + 512;          // f32 [8][8]
static constexpr size_t WS_WOUT = WS_WD   + 256;          // f32 [16][64]
static constexpr size_t WS_BK1  = WS_WOUT + 4096;         // f32 128
static constexpr size_t WS_BK2  = WS_BK1  + 512;
static constexpr size_t WS_BK3  = WS_BK2  + 512;          // f32 512
static constexpr size_t WS_BV1  = WS_BK3  + 2048;
static constexpr size_t WS_BV2  = WS_BV1  + 512;
static constexpr size_t WS_BV3  = WS_BV2  + 512;          // f32 1024
static constexpr size_t WS_BNW  = WS_BV3  + 4096;         // f32 64
static constexpr size_t WS_BNB  = WS_BNW  + 256;
// weights fragment-packed bf16 (see k_convert)
static constexpr size_t WS_WK1T = WS_BNB  + 256;          // bf16 4096
static constexpr size_t WS_WK2T = WS_WK1T + 8192;         // bf16 16384
static constexpr size_t WS_WK3T = WS_WK2T + 32768;        // bf16 65536
static constexpr size_t WS_WV1T = WS_WK3T + 131072;       // bf16 4096
static constexpr size_t WS_WV2T = WS_WV1T + 8192;         // bf16 16384
static constexpr size_t WS_WV3T = WS_WV2T + 32768;        // bf16 131072
static constexpr size_t WS_T    = WS_WV3T + 262144;       // f32 [N][16]
static constexpr size_t WS_Q    = WS_T    + (size_t)N_NODES*16*4;  // f32 [N][8]
static constexpr size_t WS_Z    = WS_Q    + (size_t)N_NODES*8*4;   // f32 [N]
static constexpr size_t WS_AGG  = WS_Z    + (size_t)N_NODES*4;     // f32 [N][16]
static constexpr size_t WS_BNS  = WS_AGG  + (size_t)N_NODES*16*4;  // f32 64
static constexpr size_t WS_BNQ  = WS_BNS  + 256;
static constexpr size_t WS_OUTP = WS_BNQ  + 256;          // f32 [N][64]
static constexpr size_t ZERO_OFF = WS_Z;
static constexpr size_t ZERO_LEN = WS_OUTP - WS_Z;

// ---------------- helpers ----------------
__device__ __forceinline__ float loadf(const void* p, long i, int isbf){
  if(isbf){
    u32 x = ((u32)((const u16*)p)[i]) << 16;
    return __uint_as_float(x);
  }
  return ((const float*)p)[i];
}
__device__ __forceinline__ u16 f2b(float f){
  u32 u = __float_as_uint(f);
  u += 0x7fffu + ((u >> 16) & 1u);
  return (u16)(u >> 16);
}
__device__ __forceinline__ float b2f(u16 v){
  return __uint_as_float(((u32)v) << 16);
}
__device__ __forceinline__ bf16x8 ld8(const u16* p){
  uint4 v = *(const uint4*)p;
  return __builtin_bit_cast(bf16x8, v);
}

// ---------------- kernels ----------------
__global__ void k_detect(const void* edge_data, int* flag){
  int lane = threadIdx.x;
  u16 v = ((const u16*)edge_data)[lane*2];
  int ex = (v >> 7) & 0xFF;
  int sane = (ex >= 100 && ex <= 140) ? 1 : 0;
  unsigned long long b = __ballot(sane);
  if(lane == 0) flag[0] = (__popcll(b) >= 48) ? 1 : 0;
}

// weights: fragment-packed. phys index p within a layer (K,N):
//   i=p&7; lane=(p>>3)&63; r2=p>>9; kk=r2%nk; r3=r2/nk; nt=r3&1; c=r3>>1;
//   n = c*32 + nt*16 + (lane&15); k = kk*32 + (lane>>4)*8 + i;  src = W[k][n]
__global__ void k_convert(InP in, char* ws){
  const int isbf = *(const int*)(ws + WS_FLAG);
  long idx = (long)blockIdx.x*256 + threadIdx.x;
  const int    fsrc[12] = {4,5,6,7,9,11,13,15,17,19,20,21};
  const int    fcnt[12] = {1024,128,64,1024,128,128,512,128,128,1024,64,64};
  const size_t fdst[12] = {WS_WIN,WS_WQ,WS_WD,WS_WOUT,WS_BK1,WS_BK2,WS_BK3,WS_BV1,WS_BV2,WS_BV3,WS_BNW,WS_BNB};
  const long F_TOTAL = 4416;
  if(idx < F_TOTAL){
    long g = idx;
    for(int s=0;s<12;s++){
      if(g < fcnt[s]){ ((float*)(ws+fdst[s]))[g] = loadf(in.p[fsrc[s]], g, isbf); return; }
      g -= fcnt[s];
    }
    return;
  }
  long g = idx - F_TOTAL;
  const int    tsrc[6] = {8,10,12,14,16,18};
  const int    tK[6]   = {32,128,128,32,128,128};
  const int    tN[6]   = {128,128,512,128,128,1024};
  const size_t tdst[6] = {WS_WK1T,WS_WK2T,WS_WK3T,WS_WV1T,WS_WV2T,WS_WV3T};
  for(int s=0;s<6;s++){
    long cnt = (long)tK[s]*tN[s];
    if(g < cnt){
      int nk = tK[s] >> 5;
      int i = (int)(g & 7), ln = (int)((g>>3) & 63);
      int r2 = (int)(g >> 9);
      int kk = r2 % nk; int r3 = r2 / nk;
      int nt = r3 & 1;  int c  = r3 >> 1;
      int n = c*32 + nt*16 + (ln & 15);
      int k = kk*32 + (ln >> 4)*8 + i;
      ((u16*)(ws+tdst[s]))[g] = f2b(loadf(in.p[tsrc[s]], (long)k*tN[s] + n, isbf));
      return;
    }
    g -= cnt;
  }
}

__global__ void k_tq(InP in, char* ws){
  const int isbf = *(const int*)(ws + WS_FLAG);
  __shared__ float sWin[1024];
  __shared__ float sWq[128];
  __shared__ float sN[1024];
  __shared__ float sT[256];
  float* t_ws = (float*)(ws+WS_T);
  float* q_ws = (float*)(ws+WS_Q);
  int tid = threadIdx.x;
  for(int i=tid;i<1024;i+=256) sWin[i] = ((const float*)(ws+WS_WIN))[i];
  if(tid<128) sWq[tid] = ((const float*)(ws+WS_WQ))[tid];
  int n0 = blockIdx.x*16;
  for(int i=tid;i<1024;i+=256) sN[i] = loadf(in.p[0], (long)n0*64 + i, isbf);
  __syncthreads();
  int ni = tid>>4, j = tid&15;
  float acc = 0.f;
  #pragma unroll 8
  for(int i=0;i<64;i++) acc += sN[ni*64+i]*sWin[i*16+j];
  float t = acc*0.125f;
  t_ws[(n0+ni)*16+j] = t;
  sT[tid] = t;
  __syncthreads();
  if(tid<128){
    int n2 = tid>>3, b = tid&7;
    float a2 = 0.f;
    #pragma unroll
    for(int jj=0;jj<16;jj++) a2 += sT[n2*16+jj]*sWq[jj*8+b];
    q_ws[(n0+n2)*8+b] = a2*0.25f;
  }
}

__global__ __launch_bounds__(256,3) void k_edges(InP in, char* ws){
  const int isbf = *(const int*)(ws + WS_FLAG);
  const int* ei = (const int*)in.p[1];
  const float* t_ws = (const float*)(ws + WS_T);
  const float* q_ws = (const float*)(ws + WS_Q);
  float* Zp  = (float*)(ws + WS_Z);
  float* AGG = (float*)(ws + WS_AGG);

  // fragment-packed LDS: H element (e,k) at tile(e>>4)*2048 + (k>>5)*512 + lane(e,k)*8 + (k&7)
  __shared__ __align__(16) char smem[51200];
  u16*   sED = (u16*)smem;               // 4096 B  [4 tiles][512]; tail overlay: sP/sDst
  u16*   sH1 = (u16*)(smem + 4096);      // 16384 B
  u16*   sH2 = (u16*)(smem + 20480);     // 16384 B
  u16*   sPT = (u16*)(smem + 36864);     // 8192 B  bf16 [as=64][e=64]
  float* sK  = (float*)(smem + 45056);   // 2048 B  [64][8]; staging alias: sh f32[64][4] (first 1 KB)
  float* sV  = (float*)(smem + 47104);   // 4096 B  [64][16]; staging alias: ts f32[64][16]
  float* sP  = (float*)smem;             // overlay on sED after it's dead
  int*   sDst= (int*)(smem + 256);

  const int tid  = threadIdx.x;
  const int e0   = blockIdx.x * 64;
  const int lane = tid & 63, wv = tid >> 6;
  const int lrow = lane & 15, lquad = lane >> 4;

  // ---- staging ----
  {
    int e = tid >> 2, q4 = tid & 3;
    u16 tmp[8];
    if(isbf){
      uint4 vv = *(const uint4*)((const u16*)in.p[2] + (long)(e0+e)*32 + q4*8);
      *(uint4*)tmp = vv;
    } else {
      const float* fp = (const float*)in.p[2] + (long)(e0+e)*32 + q4*8;
      f32x4 a = *(const f32x4*)fp, b = *(const f32x4*)(fp+4);
      #pragma unroll
      for(int r=0;r<4;r++){ tmp[r]=f2b(a[r]); tmp[4+r]=f2b(b[r]); }
    }
    *(uint4*)&sED[(e>>4)*512 + (q4*16 + (e&15))*8] = *(uint4*)tmp;
  }
  {
    int e = tid >> 2, j4 = tid & 3;
    int src = ei[e0+e];
    *(f32x4*)&sV[e*16 + j4*4] = *(const f32x4*)&t_ws[src*16 + j4*4];
  }
  {
    int e = tid >> 2, s4 = tid & 3;
    sK[tid] = loadf(in.p[3], (long)(e0+e)*4 + s4, isbf);
  }
  // wave-0 prefetches q[dst] into registers (used only at the tail)
  float qreg[8]; int mydst = 0;
  if(wv == 0){
    mydst = ei[N_EDGES + e0 + lane];
    #pragma unroll
    for(int a=0;a<8;a++) qreg[a] = q_ws[mydst*8 + a];
  }
  __syncthreads();
  for(int idx = tid; idx < 4096; idx += 256){
    int e = idx & 63, as = idx >> 6;
    sPT[as*64 + e] = f2b(sV[e*16 + (as>>2)] * sK[e*4 + (as&3)]);
  }
  __syncthreads();
  for(int idx = tid; idx < 1536; idx += 256) sK[idx] = 0.f;  // zero sK+sV (contiguous)

  // dense layer: A frag-packed (tile stride ts), weights frag-packed in global.
  auto dense = [&](const u16* A, int ts, int nkL, const u16* Wg, const float* biasg, u16* O){
    bf16x8 bw[2][4]; f32x4 bb[2];
    for(int nt=0;nt<2;nt++){
      for(int kk=0;kk<nkL;kk++)
        bw[nt][kk] = ld8(&Wg[(((wv*2+nt)*nkL + kk)<<9) + lane*8]);
      bb[nt] = *(const f32x4*)&biasg[wv*32 + nt*16 + lquad*4];
    }
    for(int et=0;et<4;et++){
      bf16x8 af[4];
      for(int kk=0;kk<nkL;kk++) af[kk] = ld8(&A[et*ts + (kk<<9) + lane*8]);
      for(int nt=0;nt<2;nt++){
        f32x4 c = {0.f,0.f,0.f,0.f};
        for(int kk=0;kk<nkL;kk++)
          c = __builtin_amdgcn_mfma_f32_16x16x32_bf16(bw[nt][kk], af[kk], c, 0, 0, 0);
        u16x4 pk;
        #pragma unroll
        for(int r=0;r<4;r++){
          float h = c[r] + bb[nt][r];
          h = h > 0.f ? h : 0.f;
          pk[r] = f2b(h);
        }
        int off = et*2048 + (wv<<9) + (nt*2 + (lquad>>1))*128 + lrow*8 + (lquad&1)*4;
        *(u16x4*)&O[off] = pk;
      }
    }
  };

  // matvec+contract: wave owns NJ 32-col chunks; weights register-double-buffered
  auto matvec = [&](const u16* Wg, const float* biasg, int NJ, int isval){
    float kp[16];
    #pragma unroll
    for(int i=0;i<16;i++) kp[i]=0.f;
    const int c0 = wv*NJ;
    bf16x8 bw[2][2][4]; f32x4 bb[2][2];
    #pragma unroll
    for(int nt=0;nt<2;nt++){
      #pragma unroll
      for(int kk=0;kk<4;kk++)
        bw[0][nt][kk] = ld8(&Wg[(((c0*2+nt)*4 + kk)<<9) + lane*8]);
      bb[0][nt] = *(const f32x4*)&biasg[c0*32 + nt*16 + lquad*4];
    }
    #pragma unroll
    for(int j=0;j<NJ;j++){
      int cur = j&1, nxt = cur^1;
      if(j+1 < NJ){
        int cn = c0 + j + 1;
        #pragma unroll
        for(int nt=0;nt<2;nt++){
          #pragma unroll
          for(int kk=0;kk<4;kk++)
            bw[nxt][nt][kk] = ld8(&Wg[(((cn*2+nt)*4 + kk)<<9) + lane*8]);
          bb[nxt][nt] = *(const f32x4*)&biasg[cn*32 + nt*16 + lquad*4];
        }
      }
      for(int et=0;et<4;et++){
        bf16x8 af[4];
        #pragma unroll
        for(int kk=0;kk<4;kk++)
          af[kk] = ld8(&sH2[et*2048 + (kk<<9) + lane*8]);
        const int e = et*16 + lrow;
        for(int nt=0;nt<2;nt++){
          f32x4 c = {0.f,0.f,0.f,0.f};
          #pragma unroll
          for(int kk=0;kk<4;kk++)
            c = __builtin_amdgcn_mfma_f32_16x16x32_bf16(bw[cur][nt][kk], af[kk], c, 0, 0, 0);
          int n0 = (c0+j)*32 + nt*16 + lquad*4;
          int as = isval ? (n0>>4) : (n0>>3);
          float pv = b2f(sPT[as*64 + e]);
          #pragma unroll
          for(int r=0;r<4;r++)
            kp[et*4+r] += pv * (c[r] + bb[cur][nt][r]);
        }
      }
    }
    if(isval){
      for(int et=0;et<4;et++){
        int e = et*16 + lrow;
        #pragma unroll
        for(int r=0;r<4;r++)
          atomicAdd(&sV[e*16 + lquad*4 + r], kp[et*4+r]*0.125f);
      }
    } else {
      int b0 = (lquad & 1)*4;
      for(int et=0;et<4;et++){
        int e = et*16 + lrow;
        #pragma unroll
        for(int r=0;r<4;r++)
          atomicAdd(&sK[e*8 + b0 + r], kp[et*4+r]*0.125f);
      }
    }
  };

  dense(sED, 512, 1, (const u16*)(ws+WS_WK1T), (const float*)(ws+WS_BK1), sH1); __syncthreads();
  dense(sH1, 2048,4, (const u16*)(ws+WS_WK2T), (const float*)(ws+WS_BK2), sH2); __syncthreads();
  matvec((const u16*)(ws+WS_WK3T), (const float*)(ws+WS_BK3), 4, 0);
  dense(sED, 512, 1, (const u16*)(ws+WS_WV1T), (const float*)(ws+WS_BV1), sH1); __syncthreads();
  dense(sH1, 2048,4, (const u16*)(ws+WS_WV2T), (const float*)(ws+WS_BV2), sH2); __syncthreads();
  matvec((const u16*)(ws+WS_WV3T), (const float*)(ws+WS_BV3), 8, 1);            __syncthreads();

  // ---- tail: logit, exp, z; then p*v -> AGG ----
  if(wv == 0){
    const float* wdf = (const float*)(ws + WS_WD);
    float acc = 0.f;
    #pragma unroll
    for(int a=0;a<8;a++){
      float qa = qreg[a];
      #pragma unroll
      for(int b=0;b<8;b++)
        acc += qa * wdf[a*8+b] * sK[lane*8+b];
    }
    float p = __expf(acc * 0.125f);
    atomicAdd(Zp + mydst, p);
    sP[lane] = p;
    sDst[lane] = mydst;
  }
  __syncthreads();
  for(int idx = tid; idx < 1024; idx += 256){
    int e = idx >> 4;
    atomicAdd(AGG + (long)sDst[e]*16 + (idx & 15), sP[e]*sV[idx]);
  }
}

__global__ void k7a(InP in, char* ws){
  const int isbf = *(const int*)(ws + WS_FLAG);
  __shared__ float sWo[1024];
  __shared__ float ls[256], lq[256];
  int tid = threadIdx.x;
  for(int i=tid;i<1024;i+=256) sWo[i] = ((const float*)(ws+WS_WOUT))[i];
  __syncthreads();
  const float* AGG = (const float*)(ws+WS_AGG);
  const float* Zp  = (const float*)(ws+WS_Z);
  float* OUTP = (float*)(ws+WS_OUTP);
  int c = tid & 63, r4 = tid >> 6;
  float s=0.f, q=0.f;
  for(int it=0; it<20; it++){
    int n = blockIdx.x*80 + it*4 + r4;
    float z = Zp[n];
    float inv = z > 0.f ? 0.25f/z : 0.f;
    const float* ag = AGG + (long)n*16;
    float acc = 0.f;
    #pragma unroll
    for(int j=0;j<16;j++) acc += ag[j]*sWo[j*64+c];
    float o = acc*inv + loadf(in.p[0], (long)n*64 + c, isbf);
    OUTP[(long)n*64+c] = o;
    s += o; q += o*o;
  }
  ls[tid]=s; lq[tid]=q;
  __syncthreads();
  if(tid < 64){
    float ss = ls[tid]+ls[tid+64]+ls[tid+128]+ls[tid+192];
    float qq = lq[tid]+lq[tid+64]+lq[tid+128]+lq[tid+192];
    atomicAdd((float*)(ws+WS_BNS)+tid, ss);
    atomicAdd((float*)(ws+WS_BNQ)+tid, qq);
  }
}

__global__ void k7c(char* ws, void* d_out){
  const int isbf = *(const int*)(ws + WS_FLAG);
  int idx = blockIdx.x*256 + threadIdx.x;
  if(idx >= N_NODES*64) return;
  int c = idx & 63;
  float s  = ((const float*)(ws+WS_BNS))[c];
  float qq = ((const float*)(ws+WS_BNQ))[c];
  float mean = s * (1.f/N_NODES);
  float var  = qq * (1.f/N_NODES) - mean*mean;
  float sc = rsqrtf(var + 1e-5f) * ((const float*)(ws+WS_BNW))[c];
  float val = (((const float*)(ws+WS_OUTP))[idx] - mean)*sc + ((const float*)(ws+WS_BNB))[c];
  if(isbf) ((u16*)d_out)[idx] = f2b(val);
  else     ((float*)d_out)[idx] = val;
}

extern "C" void kernel_launch(void* const* d_in, const int* in_sizes, int n_in,
                              void* d_out, int out_size, void* d_ws, size_t ws_size,
                              hipStream_t stream){
  InP in;
  for(int i=0;i<22;i++) in.p[i] = d_in[i];
  char* ws = (char*)d_ws;

  hipMemsetAsync(ws + ZERO_OFF, 0, ZERO_LEN, stream);
  k_detect<<<1,64,0,stream>>>((const void*)d_in[2], (int*)(ws+WS_FLAG));
  k_convert<<<946,256,0,stream>>>(in, ws);
  k_tq<<<625,256,0,stream>>>(in, ws);
  k_edges<<<2500,256,0,stream>>>(in, ws);
  k7a<<<125,256,0,stream>>>(in, ws);
  k7c<<<2500,256,0,stream>>>(ws, d_out);
}